// Round 7
// baseline (115.694 us; speedup 1.0000x reference)
//
#include <hip/hip_runtime.h>

// NCC loss: 9x9 box-filtered local cross-correlation, -mean(cc).
// Inputs: y_pred, y_true (32,4,512,512) fp32. Output: scalar fp32.
//
// R7: R6 math unchanged (passed, absmax 0). Structure changes only:
//  - TPB=64: one wave per block, 4096 blocks -> finest dispatch granularity
//    (R6's 21% occupancy with 256-thread blocks was the stall).
//  - 2-deep prefetch of the add-row (L3/HBM latency ~400-900cy) in named
//    A/B register buffers, issued 2 iterations (~1200cy) before the fold.
//    Sub-row (L1/L2-warm, read 9 rows earlier) stays 1-deep at iter top.
//  - Warm-L3 replays in R6 ran at cold speed => NOT HBM-bound; this is a
//    latency/VALU-issue problem. VALU floor at current op count ~42us.

#define PAD 4
#define EPS 1e-5f

constexpr int B = 32, C = 4, H = 512, W = 512;
constexpr int ROWS = 16;               // rows per wave-task
constexpr int NCHUNK = H / ROWS;       // 32
constexpr int NTASK = B * C * NCHUNK;  // 4096 independent waves
constexpr int TPB = 64;                // ONE wave per block
constexpr int NBLK = NTASK;            // 4096 blocks
constexpr float INV_N = 1.0f / 81.0f;

__device__ __forceinline__ void loadrow(const float* __restrict__ p, int r,
                                        int x0, float4& a, float4& b) {
    const float* q = p + (size_t)r * W + x0;
    a = *(const float4*)q;
    b = *(const float4*)(q + 4);
}

template <int SGN>
__device__ __forceinline__ void fold8(float s[5][8],
                                      const float4& i0, const float4& i1,
                                      const float4& j0, const float4& j1) {
    const float fi[8] = {i0.x, i0.y, i0.z, i0.w, i1.x, i1.y, i1.z, i1.w};
    const float fj[8] = {j0.x, j0.y, j0.z, j0.w, j1.x, j1.y, j1.z, j1.w};
#pragma unroll
    for (int k = 0; k < 8; ++k) {
        const float a = fi[k], b = fj[k];
        if (SGN > 0) {
            s[0][k] += a; s[1][k] += b;
            s[2][k] += a * a; s[3][k] += b * b; s[4][k] += a * b;
        } else {
            s[0][k] -= a; s[1][k] -= b;
            s[2][k] -= a * a; s[3][k] -= b * b; s[4][k] -= a * b;
        }
    }
}

// 9-wide window sums for 4 of this lane's 8 columns.
// HALF=0: own cols 0..3 (left halo from prev lane); HALF=1: cols 4..7.
template <int HALF>
__device__ __forceinline__ void hsum4(const float sc[8], int lane, float h[4]) {
    float v[12];
    if (HALF == 0) {
#pragma unroll
        for (int k = 0; k < 4; ++k) {
            const float t = __shfl_up(sc[4 + k], 1, 64);
            v[k] = (lane == 0) ? 0.0f : t;   // image left edge zero-pad
        }
#pragma unroll
        for (int k = 0; k < 8; ++k) v[4 + k] = sc[k];
    } else {
#pragma unroll
        for (int k = 0; k < 8; ++k) v[k] = sc[k];
#pragma unroll
        for (int k = 0; k < 4; ++k) {
            const float t = __shfl_down(sc[k], 1, 64);
            v[8 + k] = (lane == 63) ? 0.0f : t;  // image right edge zero-pad
        }
    }
    float t = v[0] + v[1] + v[2] + v[3] + v[4] + v[5] + v[6] + v[7] + v[8];
    h[0] = t;
    t += v[9]  - v[0]; h[1] = t;
    t += v[10] - v[1]; h[2] = t;
    t += v[11] - v[2]; h[3] = t;
}

__device__ __forceinline__ float cc4(const float h[5][4]) {
    float acc = 0.0f;
#pragma unroll
    for (int k = 0; k < 4; ++k) {
        const float mi = h[0][k] * INV_N;
        const float mj = h[1][k] * INV_N;
        const float vi = h[2][k] * INV_N - mi * mi;
        const float vj = h[3][k] * INV_N - mj * mj;
        const float cv = h[4][k] * INV_N - mi * mj;
        const float den = fmaxf(vi, 0.0f) * fmaxf(vj, 0.0f) + EPS;
        acc += cv * cv * __builtin_amdgcn_rcpf(den);
    }
    return acc;
}

// One output row: issue sub-row load, compute cc from current window,
// fold prefetched add-row (loaded 2 iters ago into ai*/aj*) + sub-row,
// then re-issue ai*/aj* with the add-row for iteration YO+2.
#define STEP(YO, ai0, ai1, aj0, aj1)                                         \
    {                                                                        \
        const int y = y0 + (YO);                                             \
        const int rs = y - PAD;                                              \
        const bool vsub = ((YO) < ROWS - 1) && (rs >= 0);                    \
        float4 si0, si1, sj0, sj1;                                           \
        if (vsub) {                                                          \
            loadrow(I, rs, x0, si0, si1);                                    \
            loadrow(J, rs, x0, sj0, sj1);                                    \
        }                                                                    \
        {                                                                    \
            float h[5][4];                                                   \
            hsum4<0>(s[0], lane, h[0]);                                      \
            hsum4<0>(s[1], lane, h[1]);                                      \
            hsum4<0>(s[2], lane, h[2]);                                      \
            hsum4<0>(s[3], lane, h[3]);                                      \
            hsum4<0>(s[4], lane, h[4]);                                      \
            acc += cc4(h);                                                   \
        }                                                                    \
        {                                                                    \
            float h[5][4];                                                   \
            hsum4<1>(s[0], lane, h[0]);                                      \
            hsum4<1>(s[1], lane, h[1]);                                      \
            hsum4<1>(s[2], lane, h[2]);                                      \
            hsum4<1>(s[3], lane, h[3]);                                      \
            hsum4<1>(s[4], lane, h[4]);                                      \
            acc += cc4(h);                                                   \
        }                                                                    \
        const bool va = ((YO) < ROWS - 1) && (y + PAD + 1 < H);              \
        if (va)   fold8<+1>(s, ai0, ai1, aj0, aj1);                          \
        if (vsub) fold8<-1>(s, si0, si1, sj0, sj1);                          \
        const int yn = (YO) + 2;                                             \
        const int ran = y0 + yn + PAD + 1;                                   \
        if ((yn < ROWS - 1) && (ran < H)) {                                  \
            loadrow(I, ran, x0, ai0, ai1);                                   \
            loadrow(J, ran, x0, aj0, aj1);                                   \
        }                                                                    \
    }

__global__ __launch_bounds__(TPB) void ncc_partial(
        const float* __restrict__ y_pred, const float* __restrict__ y_true,
        float* __restrict__ partial) {
    const int lane = threadIdx.x;  // one wave per block
    // XCD swizzle: consecutive tasks (vertical neighbors sharing halo rows)
    // land on the same XCD's L2. Bijective: NBLK % 8 == 0.
    const int task = (blockIdx.x & 7) * (NBLK / 8) + (blockIdx.x >> 3);
    const int plane = task >> 5;                    // / NCHUNK
    const int v = task & (NCHUNK - 1);
    const size_t base = (size_t)plane * H * W;
    const float* I = y_true + base;  // reference: I = y_true
    const float* J = y_pred + base;  // reference: J = y_pred
    const int x0 = lane * 8;
    const int y0 = v * ROWS;

    // Running vertical sums over rows [y-4, y+4]: 5 moments x 8 cols.
    float s[5][8];
#pragma unroll
    for (int c = 0; c < 5; ++c)
#pragma unroll
        for (int k = 0; k < 8; ++k) s[c][k] = 0.0f;

    // Prime rows [y0-4, y0+4] ∩ [0,H)   (y0+4 <= 500 < H always)
    for (int r = y0 - PAD; r <= y0 + PAD; ++r) {
        if (r < 0) continue;
        float4 i0, i1, j0, j1;
        loadrow(I, r, x0, i0, i1);
        loadrow(J, r, x0, j0, j1);
        fold8<+1>(s, i0, i1, j0, j1);
    }

    // 2-deep add-row prefetch: A serves even iterations, B odd.
    float4 Ai0, Ai1, Aj0, Aj1, Bi0, Bi1, Bj0, Bj1;
    {
        const int ra0 = y0 + PAD + 1;          // add-row for iter 0
        if (ra0 < H) { loadrow(I, ra0, x0, Ai0, Ai1); loadrow(J, ra0, x0, Aj0, Aj1); }
        const int ra1 = y0 + 1 + PAD + 1;      // add-row for iter 1
        if (ra1 < H) { loadrow(I, ra1, x0, Bi0, Bi1); loadrow(J, ra1, x0, Bj0, Bj1); }
    }

    float acc = 0.0f;

    for (int yo = 0; yo < ROWS; yo += 2) {
        STEP(yo,     Ai0, Ai1, Aj0, Aj1);
        STEP(yo + 1, Bi0, Bi1, Bj0, Bj1);
    }

    // Per-wave reduction; one partial per task (deterministic slot).
#pragma unroll
    for (int off = 32; off > 0; off >>= 1)
        acc += __shfl_down(acc, off, 64);
    if (lane == 0) partial[task] = acc;
}

__global__ __launch_bounds__(256) void ncc_final(
        const float* __restrict__ partial, float* __restrict__ out) {
    const int t = threadIdx.x;
    float sum = 0.0f;
    for (int i = t; i < NTASK; i += 256) sum += partial[i];
    __shared__ float ws[4];
#pragma unroll
    for (int off = 32; off > 0; off >>= 1)
        sum += __shfl_down(sum, off, 64);
    if ((t & 63) == 0) ws[t >> 6] = sum;
    __syncthreads();
    if (t == 0) {
        const float tot = ws[0] + ws[1] + ws[2] + ws[3];
        out[0] = -tot / (float)((long long)B * C * H * W);
    }
}

extern "C" void kernel_launch(void* const* d_in, const int* in_sizes, int n_in,
                              void* d_out, int out_size, void* d_ws, size_t ws_size,
                              hipStream_t stream) {
    const float* y_pred = (const float*)d_in[0];
    const float* y_true = (const float*)d_in[1];
    float* out = (float*)d_out;
    float* partial = (float*)d_ws;  // NTASK floats = 16 KB

    ncc_partial<<<NBLK, TPB, 0, stream>>>(y_pred, y_true, partial);
    ncc_final<<<1, 256, 0, stream>>>(partial, out);
}